// Round 2
// baseline (208.720 us; speedup 1.0000x reference)
//
#include <hip/hip_runtime.h>
#include <math.h>

// SEM_40200893890649: TopK_with_h + mat_GRU_cell + 2-layer GCN (fp32)
// R2: hierarchical wave-parallel top-k, fused GRU (u,r,h in one kernel),
// fused GCN (t1+h1, t2+h2+out), split gather. 7 kernels total.

namespace {
constexpr int B_ = 32;
constexpr int N_ = 2000;
constexpr int D_ = 128;
constexpr int R_ = 640;

// ---------- workspace layout (float offsets) ----------
constexpr size_t OFF_SCORER = 0;        // [32][128]
constexpr size_t OFF_INVN   = 4096;     // [32]
constexpr size_t OFF_CANDV  = 4128;     // [32][4][64]
constexpr size_t OFF_CANDI  = 12320;    // int [32][4][64]
constexpr size_t OFF_STATS  = 20512;    // [32][4][3] (m, se, sx)
constexpr size_t OFF_TKI    = 20896;    // int [32][64]
constexpr size_t OFF_T0     = 22944;    // [32][64] tanh(score) at topk
constexpr size_t OFF_NE0T   = 24992;    // [32][128][64]
constexpr size_t OFF_A0     = 287136;   // [32][64][64] RAW gathered (unnormalized)
constexpr size_t OFF_DW     = 418208;   // [32][128][128]
constexpr size_t OFF_H1     = 942496;   // [32][64][128]
// total 1204640 floats = 4.6 MiB

// ---------------- K1: scorer = tanh(ht @ mapper_w^T + b); inv_norm ----------------
__global__ __launch_bounds__(256) void k_scorer(
    const float* __restrict__ ht, const float* __restrict__ mw,
    const float* __restrict__ mb, float* __restrict__ scorer,
    float* __restrict__ invn, float* __restrict__ outScorer) {
  const int b = blockIdx.x, t = threadIdx.x;
  const int d = t & 127, half = t >> 7;
  __shared__ float sh[R_];
  __shared__ float part[2][128];
  __shared__ float red[2];
  for (int j = t; j < R_; j += 256) sh[j] = ht[b * R_ + j];
  __syncthreads();
  const float* w = mw + (size_t)d * R_ + half * 320;
  const float* hh = sh + half * 320;
  float acc = 0.f;
  for (int j = 0; j < 320; j += 4) {
    float4 wv = *reinterpret_cast<const float4*>(w + j);
    acc += wv.x * hh[j] + wv.y * hh[j + 1] + wv.z * hh[j + 2] + wv.w * hh[j + 3];
  }
  part[half][d] = acc;
  __syncthreads();
  if (t < 128) {
    float s = tanhf(part[0][t] + part[1][t] + mb[t]);
    scorer[b * D_ + t] = s;
    outScorer[b * D_ + t] = s;
    float ss = s * s;
    #pragma unroll
    for (int o = 32; o > 0; o >>= 1) ss += __shfl_down(ss, o);
    if ((t & 63) == 0) red[t >> 6] = ss;
  }
  __syncthreads();
  if (t == 0) invn[b] = 1.0f / sqrtf(red[0] + red[1]);
}

// ---------------- K2: per-chunk scores + wave-local top64 + block merge + stats ----------------
// grid (32, 4): chunk c covers rows [c*500, c*500+500)
__global__ __launch_bounds__(256) void k_score_chunk(
    const float* __restrict__ node, const float* __restrict__ scorer,
    const float* __restrict__ invn, float* __restrict__ cand_v,
    int* __restrict__ cand_i, float* __restrict__ stats) {
  const int b = blockIdx.x, c = blockIdx.y, t = threadIdx.x;
  const int lane = t & 63, w = t >> 6;
  __shared__ float sc[D_];
  __shared__ float cv[256];
  __shared__ int ci[256];
  __shared__ float red1[4], red2[4];
  if (t < D_) sc[t] = scorer[b * D_ + t];
  __syncthreads();
  const float inv = invn[b];
  const int base = c * 500;
  const int n0 = base + t;          // rows 0..255 of chunk (all valid)
  const int n1 = base + 256 + t;    // rows 256..499, valid iff t < 244
  float v0, v1 = -INFINITY;
  {
    const float* row = node + ((size_t)b * N_ + n0) * D_;
    float acc = 0.f;
    for (int j = 0; j < D_; j += 4) {
      float4 a = *reinterpret_cast<const float4*>(row + j);
      acc += a.x * sc[j] + a.y * sc[j + 1] + a.z * sc[j + 2] + a.w * sc[j + 3];
    }
    v0 = acc * inv;
  }
  if (t < 244) {
    const float* row = node + ((size_t)b * N_ + n1) * D_;
    float acc = 0.f;
    for (int j = 0; j < D_; j += 4) {
      float4 a = *reinterpret_cast<const float4*>(row + j);
      acc += a.x * sc[j] + a.y * sc[j + 1] + a.z * sc[j + 2] + a.w * sc[j + 3];
    }
    v1 = acc * inv;
  }
  // ---- chunk softmax stats: m_c, se_c = sum e^{x-m}, sx_c = sum (x-m)e^{x-m} ----
  float m = fmaxf(v0, v1);
  #pragma unroll
  for (int o = 32; o > 0; o >>= 1) m = fmaxf(m, __shfl_xor(m, o));
  if (lane == 0) red1[w] = m;
  __syncthreads();
  const float Mc = fmaxf(fmaxf(red1[0], red1[1]), fmaxf(red1[2], red1[3]));
  __syncthreads();
  float se, sx;
  {
    const float x0 = v0 - Mc;
    const float e0 = expf(x0);
    se = e0;
    sx = x0 * e0;
    if (t < 244) {
      const float x1 = v1 - Mc;
      const float e1 = expf(x1);
      se += e1;
      sx += x1 * e1;
    }
  }
  #pragma unroll
  for (int o = 32; o > 0; o >>= 1) {
    se += __shfl_xor(se, o);
    sx += __shfl_xor(sx, o);
  }
  if (lane == 0) { red1[w] = se; red2[w] = sx; }
  __syncthreads();
  if (t == 0) {
    float* st = stats + ((size_t)b * 4 + c) * 3;
    st[0] = Mc;
    st[1] = red1[0] + red1[1] + red1[2] + red1[3];
    st[2] = red2[0] + red2[1] + red2[2] + red2[3];
  }
  // ---- wave-local top-64 extraction (no barriers; wave64 lockstep) ----
  float x0 = v0, x1 = v1;
  for (int k = 0; k < 64; ++k) {
    float bv;
    int bi;
    if (x1 > x0) { bv = x1; bi = n1; } else { bv = x0; bi = n0; }
    #pragma unroll
    for (int o = 1; o < 64; o <<= 1) {
      const float ov = __shfl_xor(bv, o);
      const int oi = __shfl_xor(bi, o);
      if (ov > bv || (ov == bv && oi < bi)) { bv = ov; bi = oi; }
    }
    if (lane == 0) { cv[w * 64 + k] = bv; ci[w * 64 + k] = bi; }
    if (bi == n0) x0 = -INFINITY;
    else if (bi == n1) x1 = -INFINITY;
  }
  __syncthreads();
  // ---- block merge: rank 256 candidates, write block top-64 ----
  const float mv = cv[t];
  const int mi = ci[t];
  int rank = 0;
  for (int j = 0; j < 256; ++j) {
    const float jv = cv[j];
    const int ji = ci[j];
    rank += (jv > mv || (jv == mv && ji < mi)) ? 1 : 0;
  }
  if (rank < 64) {
    cand_v[((size_t)b * 4 + c) * 64 + rank] = mv;
    cand_i[((size_t)b * 4 + c) * 64 + rank] = mi;
  }
}

// ---------------- K3: merge 4x64 candidates -> exact top-64; policy/entropy ----------------
__global__ __launch_bounds__(256) void k_topk_merge(
    const float* __restrict__ cand_v, const int* __restrict__ cand_i,
    const float* __restrict__ stats, int* __restrict__ tki,
    float* __restrict__ t0v, float* __restrict__ outPolicy,
    float* __restrict__ outEntropy) {
  const int b = blockIdx.x, t = threadIdx.x;
  __shared__ float cv[256];
  __shared__ int ci[256];
  __shared__ float sv[64];
  __shared__ int si[64];
  cv[t] = cand_v[(size_t)b * 256 + t];
  ci[t] = cand_i[(size_t)b * 256 + t];
  __syncthreads();
  const float mv = cv[t];
  const int mi = ci[t];
  int rank = 0;
  for (int j = 0; j < 256; ++j) {
    const float jv = cv[j];
    const int ji = ci[j];
    rank += (jv > mv || (jv == mv && ji < mi)) ? 1 : 0;
  }
  if (rank < 64) { sv[rank] = mv; si[rank] = mi; }
  __syncthreads();
  if (t < 64) {
    tki[b * 64 + t] = si[t];
    t0v[b * 64 + t] = tanhf(sv[t]);
    float s = sv[t];
    #pragma unroll
    for (int o = 32; o > 0; o >>= 1) s += __shfl_xor(s, o);
    if (t == 0) {
      // online-softmax merge of 4 chunk partials
      float M = -INFINITY;
      for (int c = 0; c < 4; ++c) M = fmaxf(M, stats[((size_t)b * 4 + c) * 3]);
      float se = 0.f, sx = 0.f;
      for (int c = 0; c < 4; ++c) {
        const float* st = stats + ((size_t)b * 4 + c) * 3;
        const float f = expf(st[0] - M);
        se += f * st[1];
        sx += f * (st[2] + (st[0] - M) * st[1]);
      }
      const float logS = logf(se);
      outPolicy[b] = s * (1.0f / 64.0f) - M - logS;
      outEntropy[b] = logS - sx / se;
    }
  }
}

// ---------------- K4: gather ne0T (y=0) and raw A0 rows (y=1..4) ----------------
__global__ __launch_bounds__(256) void k_gather(
    const float* __restrict__ node, const float* __restrict__ Ahat,
    const int* __restrict__ tki, float* __restrict__ ne0T,
    float* __restrict__ A0) {
  const int b = blockIdx.x, y = blockIdx.y, t = threadIdx.x;
  __shared__ int idx[64];
  __shared__ float lne[64][132];
  if (t < 64) idx[t] = tki[b * 64 + t];
  __syncthreads();
  if (y == 0) {
    const int k = t >> 2, q = t & 3;
    const float* src = node + ((size_t)b * N_ + idx[k]) * D_ + q * 32;
    #pragma unroll
    for (int j = 0; j < 32; j += 4)
      *reinterpret_cast<float4*>(&lne[k][q * 32 + j]) =
          *reinterpret_cast<const float4*>(src + j);
    __syncthreads();
    const int f = t >> 1, kh = (t & 1) * 32;
    float* dst = ne0T + ((size_t)b * D_ + f) * 64 + kh;
    #pragma unroll
    for (int j = 0; j < 32; j += 4) {
      float4 v;
      v.x = lne[kh + j][f];
      v.y = lne[kh + j + 1][f];
      v.z = lne[kh + j + 2][f];
      v.w = lne[kh + j + 3][f];
      *reinterpret_cast<float4*>(dst + j) = v;
    }
  } else {
    const int j = t & 63, li = t >> 6;
    const int cj = idx[j];
    const float* Ab = Ahat + (size_t)b * N_ * N_;
    float* dst = A0 + (size_t)b * 64 * 64;
    #pragma unroll
    for (int s = 0; s < 4; ++s) {
      const int i = (y - 1) * 16 + s * 4 + li;
      dst[i * 64 + j] = Ab[(size_t)idx[i] * N_ + cj];
    }
  }
}

// ---------------- K5: fused GRU: u,r -> LDS; htilda; Dw ----------------
// grid (32, 4): 32-col chunks. block 256 = (16 tx) x (16 ty), thread tile 8x2.
__global__ __launch_bounds__(256) void k_gru(
    const float* __restrict__ Wu, const float* __restrict__ Uu, const float* __restrict__ bu,
    const float* __restrict__ Wr, const float* __restrict__ Ur, const float* __restrict__ br,
    const float* __restrict__ Wh, const float* __restrict__ Uh, const float* __restrict__ bh,
    const float* __restrict__ ne0T, const float* __restrict__ t0v,
    const float* __restrict__ P, float* __restrict__ Dw) {
  const int b = blockIdx.x, c = blockIdx.y;
  const int t = threadIdx.x, tx = t & 15, ty = t >> 4;
  __shared__ float Wt[16][132], Ut[16][132];
  __shared__ float Xt[16][36], Yt[16][36];
  __shared__ float gs[2][128][33];  // sigmoid gates u, r for this col-chunk
  __shared__ float t0s[32];
  if (t < 32) t0s[t] = t0v[b * 64 + (c & 1) * 32 + t];
  const float* neT = ne0T + (size_t)b * D_ * 64;
  const float* Pb = P + (size_t)b * D_ * D_;
  for (int z = 0; z < 2; ++z) {
    const float* W = z ? Wr : Wu;
    const float* U = z ? Ur : Uu;
    const float* bb = z ? br : bu;
    float acc[8][2] = {};
    for (int f0 = 0; f0 < D_; f0 += 16) {
      __syncthreads();
      #pragma unroll
      for (int rr = 0; rr < 8; rr++) {
        const int i = rr * 16 + ty;
        Wt[tx][i] = W[i * D_ + f0 + tx];
        Ut[tx][i] = U[i * D_ + f0 + tx];
      }
      {
        const int ff = ty, kk = tx * 2;
        Xt[ff][kk]     = neT[(f0 + ff) * 64 + (c & 1) * 32 + kk] * t0s[kk];
        Xt[ff][kk + 1] = neT[(f0 + ff) * 64 + (c & 1) * 32 + kk + 1] * t0s[kk + 1];
        const float2 p2 = *reinterpret_cast<const float2*>(Pb + (f0 + ff) * D_ + c * 32 + kk);
        Yt[ff][kk] = p2.x;
        Yt[ff][kk + 1] = p2.y;
      }
      __syncthreads();
      #pragma unroll
      for (int ff = 0; ff < 16; ff++) {
        const float xv0 = Xt[ff][tx * 2], xv1 = Xt[ff][tx * 2 + 1];
        const float yv0 = Yt[ff][tx * 2], yv1 = Yt[ff][tx * 2 + 1];
        const float4 wa = *reinterpret_cast<const float4*>(&Wt[ff][ty * 8]);
        const float4 wb = *reinterpret_cast<const float4*>(&Wt[ff][ty * 8 + 4]);
        const float4 ua = *reinterpret_cast<const float4*>(&Ut[ff][ty * 8]);
        const float4 ub = *reinterpret_cast<const float4*>(&Ut[ff][ty * 8 + 4]);
        const float wv[8] = {wa.x, wa.y, wa.z, wa.w, wb.x, wb.y, wb.z, wb.w};
        const float uv[8] = {ua.x, ua.y, ua.z, ua.w, ub.x, ub.y, ub.z, ub.w};
        #pragma unroll
        for (int r = 0; r < 8; r++) {
          acc[r][0] += wv[r] * xv0 + uv[r] * yv0;
          acc[r][1] += wv[r] * xv1 + uv[r] * yv1;
        }
      }
    }
    #pragma unroll
    for (int r = 0; r < 8; r++) {
      const int i = ty * 8 + r;
      #pragma unroll
      for (int cc = 0; cc < 2; cc++) {
        const int kk = tx * 2 + cc;
        const float zz = acc[r][cc] + bb[i * D_ + c * 32 + kk];
        gs[z][i][kk] = 1.f / (1.f + expf(-zz));
      }
    }
  }
  // ---- htilda phase ----
  float acc[8][2] = {};
  for (int f0 = 0; f0 < D_; f0 += 16) {
    __syncthreads();
    #pragma unroll
    for (int rr = 0; rr < 8; rr++) {
      const int i = rr * 16 + ty;
      Wt[tx][i] = Wh[i * D_ + f0 + tx];
      Ut[tx][i] = Uh[i * D_ + f0 + tx];
    }
    {
      const int ff = ty, kk = tx * 2;
      Xt[ff][kk]     = neT[(f0 + ff) * 64 + (c & 1) * 32 + kk] * t0s[kk];
      Xt[ff][kk + 1] = neT[(f0 + ff) * 64 + (c & 1) * 32 + kk + 1] * t0s[kk + 1];
      const float2 p2 = *reinterpret_cast<const float2*>(Pb + (f0 + ff) * D_ + c * 32 + kk);
      Yt[ff][kk]     = gs[1][f0 + ff][kk] * p2.x;
      Yt[ff][kk + 1] = gs[1][f0 + ff][kk + 1] * p2.y;
    }
    __syncthreads();
    #pragma unroll
    for (int ff = 0; ff < 16; ff++) {
      const float xv0 = Xt[ff][tx * 2], xv1 = Xt[ff][tx * 2 + 1];
      const float yv0 = Yt[ff][tx * 2], yv1 = Yt[ff][tx * 2 + 1];
      const float4 wa = *reinterpret_cast<const float4*>(&Wt[ff][ty * 8]);
      const float4 wb = *reinterpret_cast<const float4*>(&Wt[ff][ty * 8 + 4]);
      const float4 ua = *reinterpret_cast<const float4*>(&Ut[ff][ty * 8]);
      const float4 ub = *reinterpret_cast<const float4*>(&Ut[ff][ty * 8 + 4]);
      const float wv[8] = {wa.x, wa.y, wa.z, wa.w, wb.x, wb.y, wb.z, wb.w};
      const float uv[8] = {ua.x, ua.y, ua.z, ua.w, ub.x, ub.y, ub.z, ub.w};
      #pragma unroll
      for (int r = 0; r < 8; r++) {
        acc[r][0] += wv[r] * xv0 + uv[r] * yv0;
        acc[r][1] += wv[r] * xv1 + uv[r] * yv1;
      }
    }
  }
  #pragma unroll
  for (int r = 0; r < 8; r++) {
    const int i = ty * 8 + r;
    #pragma unroll
    for (int cc = 0; cc < 2; cc++) {
      const int kk = tx * 2 + cc;
      const int k = c * 32 + kk;
      const size_t off = ((size_t)b * D_ + i) * D_ + k;
      const float hh = tanhf(acc[r][cc] + bh[i * D_ + k]);
      const float uu = gs[0][i][kk];
      const float pp = Pb[i * D_ + k];
      Dw[off] = (1.f - uu) * pp + uu * hh;
    }
  }
}

// ---------------- K6: fused GCN layer 1: t1 = ne0 @ Dw; h1 = relu(An @ t1) ----------------
// grid (32, 2): 64-col chunks of the 128 output cols. An = 2*di_i*A0_ij*di_j in LDS.
__global__ __launch_bounds__(256) void k_gcn01(
    const float* __restrict__ ne0T, const float* __restrict__ Dw,
    const float* __restrict__ A0, float* __restrict__ h1) {
  const int b = blockIdx.x, c = blockIdx.y;
  const int t = threadIdx.x, tx = t & 15, ty = t >> 4;
  __shared__ float As[64][68];
  __shared__ float Ts[64][68];
  __shared__ float At[16][68], Bt[16][68];
  __shared__ float di[64];
  const float* A0b = A0 + (size_t)b * 64 * 64;
  #pragma unroll
  for (int p = 0; p < 4; ++p) {
    const int i = p * 16 + ty;
    *reinterpret_cast<float4*>(&As[i][tx * 4]) =
        *reinterpret_cast<const float4*>(A0b + i * 64 + tx * 4);
  }
  __syncthreads();
  if (t < 64) {
    float s = 0.f;
    #pragma unroll
    for (int i = 0; i < 64; ++i) s += As[i][t];
    di[t] = 1.0f / sqrtf(2.0f * s);
  }
  __syncthreads();
  #pragma unroll
  for (int p = 0; p < 4; ++p) {
    const int i = p * 16 + ty;
    const float sI = 2.0f * di[i];
    float4 v = *reinterpret_cast<float4*>(&As[i][tx * 4]);
    v.x *= sI * di[tx * 4];
    v.y *= sI * di[tx * 4 + 1];
    v.z *= sI * di[tx * 4 + 2];
    v.w *= sI * di[tx * 4 + 3];
    *reinterpret_cast<float4*>(&As[i][tx * 4]) = v;
  }
  // phase 1: t1 chunk (64x64) = ne0 @ Dw[:, c*64..]
  const float* neT = ne0T + (size_t)b * D_ * 64;
  const float* Db = Dw + (size_t)b * D_ * D_;
  float acc[4][4] = {};
  for (int f0 = 0; f0 < D_; f0 += 16) {
    __syncthreads();
    {
      const int ff = t >> 4, i4 = (t & 15) * 4;
      *reinterpret_cast<float4*>(&At[ff][i4]) =
          *reinterpret_cast<const float4*>(neT + (f0 + ff) * 64 + i4);
      *reinterpret_cast<float4*>(&Bt[ff][i4]) =
          *reinterpret_cast<const float4*>(Db + (f0 + ff) * D_ + c * 64 + i4);
    }
    __syncthreads();
    #pragma unroll
    for (int ff = 0; ff < 16; ff++) {
      const float4 av = *reinterpret_cast<const float4*>(&At[ff][ty * 4]);
      const float4 bv = *reinterpret_cast<const float4*>(&Bt[ff][tx * 4]);
      const float a_[4] = {av.x, av.y, av.z, av.w};
      const float b_[4] = {bv.x, bv.y, bv.z, bv.w};
      #pragma unroll
      for (int r = 0; r < 4; r++)
        #pragma unroll
        for (int cc = 0; cc < 4; cc++) acc[r][cc] += a_[r] * b_[cc];
    }
  }
  __syncthreads();
  #pragma unroll
  for (int r = 0; r < 4; r++) {
    float4 o = {acc[r][0], acc[r][1], acc[r][2], acc[r][3]};
    *reinterpret_cast<float4*>(&Ts[ty * 4 + r][tx * 4]) = o;
  }
  __syncthreads();
  // phase 2: h1 chunk = relu(An @ t1chunk)
  float acc2[4][4] = {};
  for (int ff = 0; ff < 64; ++ff) {
    const float4 bv = *reinterpret_cast<const float4*>(&Ts[ff][tx * 4]);
    const float b_[4] = {bv.x, bv.y, bv.z, bv.w};
    #pragma unroll
    for (int r = 0; r < 4; r++) {
      const float a = As[ty * 4 + r][ff];
      #pragma unroll
      for (int cc = 0; cc < 4; cc++) acc2[r][cc] += a * b_[cc];
    }
  }
  #pragma unroll
  for (int r = 0; r < 4; r++) {
    float4 o = {fmaxf(acc2[r][0], 0.f), fmaxf(acc2[r][1], 0.f),
                fmaxf(acc2[r][2], 0.f), fmaxf(acc2[r][3], 0.f)};
    *reinterpret_cast<float4*>(h1 + ((size_t)b * 64 + ty * 4 + r) * D_ + c * 64 + tx * 4) = o;
  }
}

// ---------------- K7: fused GCN layer 2: t2 = h1 @ sw; h2 = relu(An @ t2); out ----------------
__global__ __launch_bounds__(256) void k_gcn23(
    const float* __restrict__ h1, const float* __restrict__ sw,
    const float* __restrict__ A0, float* __restrict__ out) {
  const int b = blockIdx.x, c = blockIdx.y;
  const int t = threadIdx.x, tx = t & 15, ty = t >> 4;
  __shared__ float As[64][68];
  __shared__ float Ts[64][68];
  __shared__ float At[16][68], Bt[16][68];
  __shared__ float di[64];
  const float* A0b = A0 + (size_t)b * 64 * 64;
  #pragma unroll
  for (int p = 0; p < 4; ++p) {
    const int i = p * 16 + ty;
    *reinterpret_cast<float4*>(&As[i][tx * 4]) =
        *reinterpret_cast<const float4*>(A0b + i * 64 + tx * 4);
  }
  __syncthreads();
  if (t < 64) {
    float s = 0.f;
    #pragma unroll
    for (int i = 0; i < 64; ++i) s += As[i][t];
    di[t] = 1.0f / sqrtf(2.0f * s);
  }
  __syncthreads();
  #pragma unroll
  for (int p = 0; p < 4; ++p) {
    const int i = p * 16 + ty;
    const float sI = 2.0f * di[i];
    float4 v = *reinterpret_cast<float4*>(&As[i][tx * 4]);
    v.x *= sI * di[tx * 4];
    v.y *= sI * di[tx * 4 + 1];
    v.z *= sI * di[tx * 4 + 2];
    v.w *= sI * di[tx * 4 + 3];
    *reinterpret_cast<float4*>(&As[i][tx * 4]) = v;
  }
  // phase 1: t2 chunk = h1 @ sw[:, c*64..]
  const float* h1b = h1 + (size_t)b * 64 * D_;
  float acc[4][4] = {};
  for (int f0 = 0; f0 < D_; f0 += 16) {
    __syncthreads();
    {
      const int ff = t >> 4, i4 = (t & 15) * 4;
      #pragma unroll
      for (int s = 0; s < 4; ++s) At[ff][i4 + s] = h1b[(i4 + s) * D_ + f0 + ff];
      *reinterpret_cast<float4*>(&Bt[ff][i4]) =
          *reinterpret_cast<const float4*>(sw + (f0 + ff) * D_ + c * 64 + i4);
    }
    __syncthreads();
    #pragma unroll
    for (int ff = 0; ff < 16; ff++) {
      const float4 av = *reinterpret_cast<const float4*>(&At[ff][ty * 4]);
      const float4 bv = *reinterpret_cast<const float4*>(&Bt[ff][tx * 4]);
      const float a_[4] = {av.x, av.y, av.z, av.w};
      const float b_[4] = {bv.x, bv.y, bv.z, bv.w};
      #pragma unroll
      for (int r = 0; r < 4; r++)
        #pragma unroll
        for (int cc = 0; cc < 4; cc++) acc[r][cc] += a_[r] * b_[cc];
    }
  }
  __syncthreads();
  #pragma unroll
  for (int r = 0; r < 4; r++) {
    float4 o = {acc[r][0], acc[r][1], acc[r][2], acc[r][3]};
    *reinterpret_cast<float4*>(&Ts[ty * 4 + r][tx * 4]) = o;
  }
  __syncthreads();
  // phase 2: h2 chunk = relu(An @ t2chunk); out = 0.5*(h1+h2), rows duplicated
  float acc2[4][4] = {};
  for (int ff = 0; ff < 64; ++ff) {
    const float4 bv = *reinterpret_cast<const float4*>(&Ts[ff][tx * 4]);
    const float b_[4] = {bv.x, bv.y, bv.z, bv.w};
    #pragma unroll
    for (int r = 0; r < 4; r++) {
      const float a = As[ty * 4 + r][ff];
      #pragma unroll
      for (int cc = 0; cc < 4; cc++) acc2[r][cc] += a * b_[cc];
    }
  }
  #pragma unroll
  for (int r = 0; r < 4; r++) {
    const int i = ty * 4 + r;
    const int k = c * 64 + tx * 4;
    const float4 h1v = *reinterpret_cast<const float4*>(h1b + i * D_ + k);
    float4 o;
    o.x = 0.5f * (h1v.x + fmaxf(acc2[r][0], 0.f));
    o.y = 0.5f * (h1v.y + fmaxf(acc2[r][1], 0.f));
    o.z = 0.5f * (h1v.z + fmaxf(acc2[r][2], 0.f));
    o.w = 0.5f * (h1v.w + fmaxf(acc2[r][3], 0.f));
    *reinterpret_cast<float4*>(out + ((size_t)b * D_ + i) * D_ + k) = o;
    *reinterpret_cast<float4*>(out + ((size_t)b * D_ + i + 64) * D_ + k) = o;
  }
}

}  // namespace

extern "C" void kernel_launch(void* const* d_in, const int* in_sizes, int n_in,
                              void* d_out, int out_size, void* d_ws, size_t ws_size,
                              hipStream_t stream) {
  (void)in_sizes; (void)n_in; (void)out_size; (void)ws_size;
  const float* Ahat = (const float*)d_in[0];
  const float* node = (const float*)d_in[1];
  const float* ht   = (const float*)d_in[2];
  const float* prevD= (const float*)d_in[3];
  const float* mw   = (const float*)d_in[4];
  const float* mb   = (const float*)d_in[5];
  const float* Wu   = (const float*)d_in[6];
  const float* Uu   = (const float*)d_in[7];
  const float* bu   = (const float*)d_in[8];
  const float* Wr   = (const float*)d_in[9];
  const float* Ur   = (const float*)d_in[10];
  const float* br   = (const float*)d_in[11];
  const float* Wh   = (const float*)d_in[12];
  const float* Uh   = (const float*)d_in[13];
  const float* bh   = (const float*)d_in[14];
  const float* sw   = (const float*)d_in[15];

  float* out = (float*)d_out;
  float* outPolicy  = out + (size_t)B_ * D_ * D_;
  float* outScorer  = outPolicy + B_;
  float* outEntropy = outScorer + (size_t)B_ * D_;

  float* ws = (float*)d_ws;
  float* scorer = ws + OFF_SCORER;
  float* invn   = ws + OFF_INVN;
  float* cand_v = ws + OFF_CANDV;
  int*   cand_i = (int*)(ws + OFF_CANDI);
  float* stats  = ws + OFF_STATS;
  int*   tki    = (int*)(ws + OFF_TKI);
  float* t0v    = ws + OFF_T0;
  float* ne0T   = ws + OFF_NE0T;
  float* A0     = ws + OFF_A0;
  float* Dw     = ws + OFF_DW;
  float* h1     = ws + OFF_H1;

  k_scorer<<<B_, 256, 0, stream>>>(ht, mw, mb, scorer, invn, outScorer);
  k_score_chunk<<<dim3(B_, 4), 256, 0, stream>>>(node, scorer, invn, cand_v, cand_i, stats);
  k_topk_merge<<<B_, 256, 0, stream>>>(cand_v, cand_i, stats, tki, t0v, outPolicy, outEntropy);
  k_gather<<<dim3(B_, 5), 256, 0, stream>>>(node, Ahat, tki, ne0T, A0);
  k_gru<<<dim3(B_, 4), 256, 0, stream>>>(Wu, Uu, bu, Wr, Ur, br, Wh, Uh, bh,
                                         ne0T, t0v, prevD, Dw);
  k_gcn01<<<dim3(B_, 2), 256, 0, stream>>>(ne0T, Dw, A0, h1);
  k_gcn23<<<dim3(B_, 2), 256, 0, stream>>>(h1, sw, A0, out);
}